// Round 1
// baseline (510.017 us; speedup 1.0000x reference)
//
#include <hip/hip_runtime.h>
#include <stdint.h>
#include <math.h>

typedef unsigned short u16;
typedef __attribute__((ext_vector_type(8))) __bf16 bf16x8;
typedef __attribute__((ext_vector_type(4))) float f32x4;

#define NB 16
#define NSQ 512
#define NSE 512
#define ND 512
#define NH 8
#define NDH 64
#define NDFF 2048

__device__ __forceinline__ u16 f2b(float f) {
  uint32_t u = __float_as_uint(f);
  u = (u + 0x7FFFu + ((u >> 16) & 1u)) >> 16;
  return (u16)u;
}
__device__ __forceinline__ float b2f(uint32_t h) {
  return __uint_as_float(h << 16);
}

// ---------------- elementwise f32 -> bf16 cast (8 elems/thread) ----------------
__global__ void k_cast_bf16(const float* __restrict__ x, u16* __restrict__ y) {
  const int i = blockIdx.x * 256 + threadIdx.x;
  const float4* p = (const float4*)(x + (size_t)i * 8);
  float4 v0 = p[0], v1 = p[1];
  uint4 o;
  o.x = (uint32_t)f2b(v0.x) | ((uint32_t)f2b(v0.y) << 16);
  o.y = (uint32_t)f2b(v0.z) | ((uint32_t)f2b(v0.w) << 16);
  o.z = (uint32_t)f2b(v1.x) | ((uint32_t)f2b(v1.y) << 16);
  o.w = (uint32_t)f2b(v1.z) | ((uint32_t)f2b(v1.w) << 16);
  *(uint4*)(y + (size_t)i * 8) = o;
}

// ---------------- weight transpose + cast: W[K,N] f32 -> Wt[N,K] bf16 ----------
__global__ void k_transpose_cast(const float* __restrict__ W, u16* __restrict__ Wt,
                                 int K, int N) {
  __shared__ float t[32][33];
  const int n0 = blockIdx.x * 32, k0 = blockIdx.y * 32;
  const int tx = threadIdx.x, ty = threadIdx.y;  // 32 x 8
#pragma unroll
  for (int i = 0; i < 32; i += 8)
    t[ty + i][tx] = W[(size_t)(k0 + ty + i) * N + n0 + tx];
  __syncthreads();
#pragma unroll
  for (int i = 0; i < 32; i += 8)
    Wt[(size_t)(n0 + ty + i) * K + k0 + tx] = f2b(t[tx][ty + i]);
}

// ---------------- main GEMM: C = epi(A[M,K] * Bt[N,K]^T + bias) ----------------
// A,Bt bf16 row-major; 128x128 tile, BK=64, 4 waves (2x2), 16x16x32 MFMA.
enum { EPI_QK = 0, EPI_V = 1, EPI_GELU = 2, EPI_RELU = 3, EPI_NONE = 4 };

template <int EPI>
__global__ __launch_bounds__(256, 2) void k_gemm_bt(
    const u16* __restrict__ A, const u16* __restrict__ Bt,
    const float* __restrict__ bias, u16* __restrict__ out, int K, int N) {
  __shared__ u16 As[128 * 64];
  __shared__ u16 Bs[128 * 64];
  const int tid = threadIdx.x, lane = tid & 63, wid = tid >> 6;
  const int wr = wid >> 1, wc = wid & 1;
  const int brow = blockIdx.x * 128, bcol = blockIdx.y * 128;
  const int srow = tid >> 3, scol = (tid & 7) * 8;
  f32x4 acc[4][4] = {};
  for (int k0 = 0; k0 < K; k0 += 64) {
#pragma unroll
    for (int v = 0; v < 4; ++v) {
      const int row = v * 32 + srow;
      *(uint4*)(As + row * 64 + scol) =
          *(const uint4*)(A + (size_t)(brow + row) * K + k0 + scol);
      *(uint4*)(Bs + row * 64 + scol) =
          *(const uint4*)(Bt + (size_t)(bcol + row) * K + k0 + scol);
    }
    __syncthreads();
#pragma unroll
    for (int kk = 0; kk < 2; ++kk) {
      bf16x8 af[4], bfr[4];
#pragma unroll
      for (int m = 0; m < 4; ++m)
        af[m] = *(const bf16x8*)(As + (wr * 64 + m * 16 + (lane & 15)) * 64 +
                                 kk * 32 + (lane >> 4) * 8);
#pragma unroll
      for (int n = 0; n < 4; ++n)
        bfr[n] = *(const bf16x8*)(Bs + (wc * 64 + n * 16 + (lane & 15)) * 64 +
                                  kk * 32 + (lane >> 4) * 8);
#pragma unroll
      for (int m = 0; m < 4; ++m)
#pragma unroll
        for (int n = 0; n < 4; ++n)
          acc[m][n] =
              __builtin_amdgcn_mfma_f32_16x16x32_bf16(af[m], bfr[n], acc[m][n], 0, 0, 0);
    }
    __syncthreads();
  }
#pragma unroll
  for (int m = 0; m < 4; ++m) {
    const int r0 = brow + wr * 64 + m * 16 + (lane >> 4) * 4;
#pragma unroll
    for (int n = 0; n < 4; ++n) {
      const int col = bcol + wc * 64 + n * 16 + (lane & 15);
      const float bv = bias[col];
#pragma unroll
      for (int j = 0; j < 4; ++j) {
        const int r = r0 + j;
        float vv = acc[m][n][j] + bv;
        if (EPI == EPI_QK) {
          const int b = r >> 9, s = r & 511, h = col >> 6, d = col & 63;
          out[((size_t)(b * NH + h) * NSQ + s) * NDH + d] = f2b(vv);
        } else if (EPI == EPI_V) {
          const int b = r >> 9, s = r & 511, h = col >> 6, d = col & 63;
          out[((size_t)(b * NH + h) * NDH + d) * NSE + s] = f2b(vv);
        } else {
          if (EPI == EPI_GELU) vv = 0.5f * vv * (1.0f + erff(vv * 0.70710678118654752f));
          if (EPI == EPI_RELU) vv = fmaxf(vv, 0.0f);
          out[(size_t)r * N + col] = f2b(vv);
        }
      }
    }
  }
}

// ---------------- attention logits: S = Q*K^T/8 + mask, f32 to aw region -------
template <int CAUSAL>
__global__ __launch_bounds__(256, 2) void k_attn_logits(
    const u16* __restrict__ qh, const u16* __restrict__ kh,
    const float* __restrict__ pmask, float* __restrict__ aw) {
  const int bh = blockIdx.z, b = bh >> 3;
  const u16* Q = qh + (size_t)bh * NSQ * NDH;
  const u16* Kh = kh + (size_t)bh * NSE * NDH;
  float* outp = aw + (size_t)bh * NSQ * NSE;
  __shared__ u16 Qs[128 * 64];
  __shared__ u16 Ks[128 * 64];
  const int tid = threadIdx.x, lane = tid & 63, wid = tid >> 6;
  const int wr = wid >> 1, wc = wid & 1;
  const int brow = blockIdx.x * 128, bcol = blockIdx.y * 128;
  const int srow = tid >> 3, scol = (tid & 7) * 8;
#pragma unroll
  for (int v = 0; v < 4; ++v) {
    const int row = v * 32 + srow;
    *(uint4*)(Qs + row * 64 + scol) = *(const uint4*)(Q + (size_t)(brow + row) * NDH + scol);
    *(uint4*)(Ks + row * 64 + scol) = *(const uint4*)(Kh + (size_t)(bcol + row) * NDH + scol);
  }
  __syncthreads();
  f32x4 acc[4][4] = {};
#pragma unroll
  for (int kk = 0; kk < 2; ++kk) {
    bf16x8 af[4], bfr[4];
#pragma unroll
    for (int m = 0; m < 4; ++m)
      af[m] = *(const bf16x8*)(Qs + (wr * 64 + m * 16 + (lane & 15)) * 64 +
                               kk * 32 + (lane >> 4) * 8);
#pragma unroll
    for (int n = 0; n < 4; ++n)
      bfr[n] = *(const bf16x8*)(Ks + (wc * 64 + n * 16 + (lane & 15)) * 64 +
                                kk * 32 + (lane >> 4) * 8);
#pragma unroll
    for (int m = 0; m < 4; ++m)
#pragma unroll
      for (int n = 0; n < 4; ++n)
        acc[m][n] =
            __builtin_amdgcn_mfma_f32_16x16x32_bf16(af[m], bfr[n], acc[m][n], 0, 0, 0);
  }
#pragma unroll
  for (int m = 0; m < 4; ++m) {
    const int r0 = brow + wr * 64 + m * 16 + (lane >> 4) * 4;
#pragma unroll
    for (int n = 0; n < 4; ++n) {
      const int col = bcol + wc * 64 + n * 16 + (lane & 15);
      const float pm = CAUSAL ? 0.0f : pmask[b * NSE + col] * (-1e9f);
#pragma unroll
      for (int j = 0; j < 4; ++j) {
        const int r = r0 + j;
        float vv = acc[m][n][j] * 0.125f;
        if (CAUSAL) {
          if (col > r) vv -= 1e9f;
        } else {
          vv += pm;
        }
        outp[(size_t)r * NSE + col] = vv;
      }
    }
  }
}

// ---------------- in-place row softmax (one wave per 512-row) ------------------
__global__ __launch_bounds__(256) void k_softmax(float* __restrict__ aw) {
  const int row = blockIdx.x * 4 + (threadIdx.x >> 6);
  const int lane = threadIdx.x & 63;
  float* p = aw + (size_t)row * 512 + lane * 8;
  float4 v0 = *(float4*)p, v1 = *(float4*)(p + 4);
  float mx = fmaxf(fmaxf(fmaxf(v0.x, v0.y), fmaxf(v0.z, v0.w)),
                   fmaxf(fmaxf(v1.x, v1.y), fmaxf(v1.z, v1.w)));
#pragma unroll
  for (int o = 1; o < 64; o <<= 1) mx = fmaxf(mx, __shfl_xor(mx, o, 64));
  v0.x = __expf(v0.x - mx); v0.y = __expf(v0.y - mx);
  v0.z = __expf(v0.z - mx); v0.w = __expf(v0.w - mx);
  v1.x = __expf(v1.x - mx); v1.y = __expf(v1.y - mx);
  v1.z = __expf(v1.z - mx); v1.w = __expf(v1.w - mx);
  float s = v0.x + v0.y + v0.z + v0.w + v1.x + v1.y + v1.z + v1.w;
#pragma unroll
  for (int o = 1; o < 64; o <<= 1) s += __shfl_xor(s, o, 64);
  const float inv = 1.0f / s;
  v0.x *= inv; v0.y *= inv; v0.z *= inv; v0.w *= inv;
  v1.x *= inv; v1.y *= inv; v1.z *= inv; v1.w *= inv;
  *(float4*)p = v0;
  *(float4*)(p + 4) = v1;
}

// ---------------- PV: ctx[b,s,h*64+d] = sum_k P[b,h,s,k] * V[b,h,k,d] ----------
// P f32 (aw), staged to bf16; V given transposed vt[b,h,d,k].
__global__ __launch_bounds__(256, 2) void k_attn_pv(const float* __restrict__ aw,
                                                    const u16* __restrict__ vt,
                                                    u16* __restrict__ ctx) {
  const int bh = blockIdx.z, b = bh >> 3, h = bh & 7;
  const float* P = aw + (size_t)bh * NSQ * NSE;
  const u16* V = vt + (size_t)bh * NDH * NSE;  // [64][512]
  __shared__ u16 Ps[128 * 64];
  __shared__ u16 Vs[64 * 64];
  const int tid = threadIdx.x, lane = tid & 63, wid = tid >> 6;
  const int brow = blockIdx.x * 128;
  const int prow = tid >> 4, pcol = (tid & 15) * 4;
  const int srow = tid >> 3, scol = (tid & 7) * 8;
  f32x4 acc[2][4] = {};
  for (int k0 = 0; k0 < NSE; k0 += 64) {
#pragma unroll
    for (int pass = 0; pass < 8; ++pass) {
      const int row = pass * 16 + prow;
      float4 v = *(const float4*)(P + (size_t)(brow + row) * NSE + k0 + pcol);
      uint2 o;
      o.x = (uint32_t)f2b(v.x) | ((uint32_t)f2b(v.y) << 16);
      o.y = (uint32_t)f2b(v.z) | ((uint32_t)f2b(v.w) << 16);
      *(uint2*)(Ps + row * 64 + pcol) = o;
    }
#pragma unroll
    for (int v = 0; v < 2; ++v) {
      const int row = v * 32 + srow;
      *(uint4*)(Vs + row * 64 + scol) = *(const uint4*)(V + (size_t)row * NSE + k0 + scol);
    }
    __syncthreads();
#pragma unroll
    for (int kk = 0; kk < 2; ++kk) {
      bf16x8 af[2], bfr[4];
#pragma unroll
      for (int m = 0; m < 2; ++m)
        af[m] = *(const bf16x8*)(Ps + (wid * 32 + m * 16 + (lane & 15)) * 64 +
                                 kk * 32 + (lane >> 4) * 8);
#pragma unroll
      for (int n = 0; n < 4; ++n)
        bfr[n] = *(const bf16x8*)(Vs + (n * 16 + (lane & 15)) * 64 + kk * 32 +
                                  (lane >> 4) * 8);
#pragma unroll
      for (int m = 0; m < 2; ++m)
#pragma unroll
        for (int n = 0; n < 4; ++n)
          acc[m][n] =
              __builtin_amdgcn_mfma_f32_16x16x32_bf16(af[m], bfr[n], acc[m][n], 0, 0, 0);
    }
    __syncthreads();
  }
#pragma unroll
  for (int m = 0; m < 2; ++m) {
    const int r0 = brow + wid * 32 + m * 16 + (lane >> 4) * 4;
#pragma unroll
    for (int n = 0; n < 4; ++n) {
      const int col = n * 16 + (lane & 15);
#pragma unroll
      for (int j = 0; j < 4; ++j) {
        const int r = r0 + j;
        ctx[((size_t)(b * NSQ + r)) * ND + h * NDH + col] = f2b(acc[m][n][j]);
      }
    }
  }
}

// ---------------- residual + LayerNorm (one wave per 512-row) ------------------
template <int B_BF16, int OUT_F32>
__global__ __launch_bounds__(256) void k_res_ln(const u16* __restrict__ a,
                                                const void* __restrict__ bsrc,
                                                const float* __restrict__ g,
                                                const float* __restrict__ bet,
                                                void* __restrict__ outp) {
  const int row = blockIdx.x * 4 + (threadIdx.x >> 6);
  const int lane = threadIdx.x & 63;
  const size_t base = (size_t)row * 512 + lane * 8;
  float s[8];
  {
    uint4 av = *(const uint4*)(a + base);
    s[0] = b2f(av.x & 0xffffu); s[1] = b2f(av.x >> 16);
    s[2] = b2f(av.y & 0xffffu); s[3] = b2f(av.y >> 16);
    s[4] = b2f(av.z & 0xffffu); s[5] = b2f(av.z >> 16);
    s[6] = b2f(av.w & 0xffffu); s[7] = b2f(av.w >> 16);
  }
  if (B_BF16) {
    uint4 bv = *(const uint4*)((const u16*)bsrc + base);
    s[0] += b2f(bv.x & 0xffffu); s[1] += b2f(bv.x >> 16);
    s[2] += b2f(bv.y & 0xffffu); s[3] += b2f(bv.y >> 16);
    s[4] += b2f(bv.z & 0xffffu); s[5] += b2f(bv.z >> 16);
    s[6] += b2f(bv.w & 0xffffu); s[7] += b2f(bv.w >> 16);
  } else {
    const float* bp = (const float*)bsrc + base;
    float4 b0 = *(const float4*)bp, b1 = *(const float4*)(bp + 4);
    s[0] += b0.x; s[1] += b0.y; s[2] += b0.z; s[3] += b0.w;
    s[4] += b1.x; s[5] += b1.y; s[6] += b1.z; s[7] += b1.w;
  }
  float sum = 0.f;
#pragma unroll
  for (int i = 0; i < 8; ++i) sum += s[i];
#pragma unroll
  for (int o = 1; o < 64; o <<= 1) sum += __shfl_xor(sum, o, 64);
  const float mu = sum * (1.0f / 512.0f);
  float vs = 0.f;
#pragma unroll
  for (int i = 0; i < 8; ++i) {
    const float d = s[i] - mu;
    vs += d * d;
  }
#pragma unroll
  for (int o = 1; o < 64; o <<= 1) vs += __shfl_xor(vs, o, 64);
  const float rs = rsqrtf(vs * (1.0f / 512.0f) + 1e-6f);
  float y[8];
#pragma unroll
  for (int i = 0; i < 8; ++i) {
    const int c = lane * 8 + i;
    y[i] = (s[i] - mu) * rs * g[c] + bet[c];
  }
  if (OUT_F32) {
    float* op = (float*)outp + base;
    *(float4*)op = make_float4(y[0], y[1], y[2], y[3]);
    *(float4*)(op + 4) = make_float4(y[4], y[5], y[6], y[7]);
  } else {
    uint4 o;
    o.x = (uint32_t)f2b(y[0]) | ((uint32_t)f2b(y[1]) << 16);
    o.y = (uint32_t)f2b(y[2]) | ((uint32_t)f2b(y[3]) << 16);
    o.z = (uint32_t)f2b(y[4]) | ((uint32_t)f2b(y[5]) << 16);
    o.w = (uint32_t)f2b(y[6]) | ((uint32_t)f2b(y[7]) << 16);
    *(uint4*)((u16*)outp + base) = o;
  }
}

extern "C" void kernel_launch(void* const* d_in, const int* in_sizes, int n_in,
                              void* d_out, int out_size, void* d_ws, size_t ws_size,
                              hipStream_t stream) {
  (void)in_sizes; (void)n_in; (void)out_size; (void)ws_size;
  const float* x = (const float*)d_in[0];
  const float* enc_fc = (const float*)d_in[1];
  const float* enc_ff = (const float*)d_in[2];
  const float* pmask = (const float*)d_in[4];
  const float* w_m1[4] = {(const float*)d_in[5], (const float*)d_in[7],
                          (const float*)d_in[9], (const float*)d_in[11]};
  const float* b_m1[4] = {(const float*)d_in[6], (const float*)d_in[8],
                          (const float*)d_in[10], (const float*)d_in[12]};
  const float* w_m2[4] = {(const float*)d_in[13], (const float*)d_in[15],
                          (const float*)d_in[17], (const float*)d_in[19]};
  const float* b_m2[4] = {(const float*)d_in[14], (const float*)d_in[16],
                          (const float*)d_in[18], (const float*)d_in[20]};
  const float* ffn_w1 = (const float*)d_in[21];
  const float* ffn_b1 = (const float*)d_in[22];
  const float* ffn_w2 = (const float*)d_in[23];
  const float* ffn_b2 = (const float*)d_in[24];
  const float* ln_g[3] = {(const float*)d_in[25], (const float*)d_in[27],
                          (const float*)d_in[29]};
  const float* ln_b[3] = {(const float*)d_in[26], (const float*)d_in[28],
                          (const float*)d_in[30]};

  char* ws = (char*)d_ws;
  const size_t SZB = (size_t)8192 * 512 * 2;  // 8 MiB bf16 activation buffer
  u16* xb = (u16*)(ws + 0 * SZB);
  u16* fcb = (u16*)(ws + 1 * SZB);
  u16* ffb = (u16*)(ws + 2 * SZB);
  u16* qh = (u16*)(ws + 3 * SZB);
  u16* kh = (u16*)(ws + 4 * SZB);
  u16* vt = (u16*)(ws + 5 * SZB);
  u16* ctx = (u16*)(ws + 6 * SZB);
  u16* ao = (u16*)(ws + 7 * SZB);
  u16* out1 = (u16*)(ws + 8 * SZB);
  u16* out2 = (u16*)(ws + 9 * SZB);
  u16* ffv = (u16*)(ws + 10 * SZB);
  u16* ff1 = (u16*)(ws + 11 * SZB);                          // 32 MiB
  u16* wts = (u16*)(ws + 11 * SZB + (size_t)8192 * 2048 * 2);
  u16* wt_m1[4], *wt_m2[4];
  for (int i = 0; i < 4; ++i) {
    wt_m1[i] = wts + (size_t)i * 262144;
    wt_m2[i] = wts + (size_t)(4 + i) * 262144;
  }
  u16* w1t = wts + (size_t)8 * 262144;      // [2048,512]
  u16* w2t = w1t + (size_t)2048 * 512;      // [512,2048]

  float* out3 = (float*)d_out;
  float* aw1 = out3 + (size_t)NB * NSQ * ND;
  float* aw2 = aw1 + (size_t)NB * NH * NSQ * NSQ;

  // casts
  k_cast_bf16<<<2048, 256, 0, stream>>>(x, xb);
  k_cast_bf16<<<2048, 256, 0, stream>>>(enc_fc, fcb);
  k_cast_bf16<<<2048, 256, 0, stream>>>(enc_ff, ffb);

  // weight transposes
  dim3 tb(32, 8);
  for (int i = 0; i < 4; ++i) {
    k_transpose_cast<<<dim3(16, 16), tb, 0, stream>>>(w_m1[i], wt_m1[i], 512, 512);
    k_transpose_cast<<<dim3(16, 16), tb, 0, stream>>>(w_m2[i], wt_m2[i], 512, 512);
  }
  k_transpose_cast<<<dim3(64, 16), tb, 0, stream>>>(ffn_w1, w1t, 512, 2048);
  k_transpose_cast<<<dim3(16, 64), tb, 0, stream>>>(ffn_w2, w2t, 2048, 512);

  const dim3 g512(64, 4), g2048(64, 16);
  // MHA1 (self, causal)
  k_gemm_bt<EPI_QK><<<g512, 256, 0, stream>>>(xb, wt_m1[0], b_m1[0], qh, 512, 512);
  k_gemm_bt<EPI_QK><<<g512, 256, 0, stream>>>(xb, wt_m1[1], b_m1[1], kh, 512, 512);
  k_gemm_bt<EPI_V><<<g512, 256, 0, stream>>>(xb, wt_m1[2], b_m1[2], vt, 512, 512);
  k_attn_logits<1><<<dim3(4, 4, 128), 256, 0, stream>>>(qh, kh, nullptr, aw1);
  k_softmax<<<16384, 256, 0, stream>>>(aw1);
  k_attn_pv<<<dim3(4, 1, 128), 256, 0, stream>>>(aw1, vt, ctx);
  k_gemm_bt<EPI_GELU><<<g512, 256, 0, stream>>>(ctx, wt_m1[3], b_m1[3], ao, 512, 512);
  k_res_ln<0, 0><<<2048, 256, 0, stream>>>(ao, x, ln_g[0], ln_b[0], out1);
  // MHA2 (cross, padding mask): q=out1, k=enc_fc, v=enc_ff
  k_gemm_bt<EPI_QK><<<g512, 256, 0, stream>>>(out1, wt_m2[0], b_m2[0], qh, 512, 512);
  k_gemm_bt<EPI_QK><<<g512, 256, 0, stream>>>(fcb, wt_m2[1], b_m2[1], kh, 512, 512);
  k_gemm_bt<EPI_V><<<g512, 256, 0, stream>>>(ffb, wt_m2[2], b_m2[2], vt, 512, 512);
  k_attn_logits<0><<<dim3(4, 4, 128), 256, 0, stream>>>(qh, kh, pmask, aw2);
  k_softmax<<<16384, 256, 0, stream>>>(aw2);
  k_attn_pv<<<dim3(4, 1, 128), 256, 0, stream>>>(aw2, vt, ctx);
  k_gemm_bt<EPI_GELU><<<g512, 256, 0, stream>>>(ctx, wt_m2[3], b_m2[3], ao, 512, 512);
  k_res_ln<1, 0><<<2048, 256, 0, stream>>>(ao, out1, ln_g[1], ln_b[1], out2);
  // FFN
  k_gemm_bt<EPI_RELU><<<g2048, 256, 0, stream>>>(out2, w1t, ffn_b1, ff1, 512, 2048);
  k_gemm_bt<EPI_NONE><<<g512, 256, 0, stream>>>(ff1, w2t, ffn_b2, ffv, 2048, 512);
  k_res_ln<1, 1><<<2048, 256, 0, stream>>>(ffv, out2, ln_g[2], ln_b[2], (void*)d_out);
}